// Round 1
// baseline (4478.790 us; speedup 1.0000x reference)
//
#include <hip/hip_runtime.h>
#include <cmath>

#define N_NODES 50000
#define N_EDGES 800000
#define IN_FEAT 256
#define HIDDEN  512
#define NUM_LAYERS 4

// ---------------- CSR build ----------------

__global__ void hist_kernel(const int* __restrict__ dst, int* __restrict__ counts, int E) {
    int e = blockIdx.x * blockDim.x + threadIdx.x;
    if (e < E) atomicAdd(&counts[dst[e]], 1);
}

// Single-block exclusive scan of cnt[0..n) -> offs[0..n]; also resets cnt[i]=offs[i]
// so it can serve as the fill cursor.
__global__ __launch_bounds__(1024) void scan_kernel(int* __restrict__ cnt, int* __restrict__ offs, int n) {
    __shared__ int partial[1024];
    const int tid = threadIdx.x;
    const int chunk = (n + 1023) / 1024;
    int start = tid * chunk;
    int end = start + chunk; if (end > n) end = n; if (start > n) start = n;
    int sum = 0;
    for (int i = start; i < end; ++i) sum += cnt[i];
    partial[tid] = sum;
    __syncthreads();
    for (int off = 1; off < 1024; off <<= 1) {
        int v = (tid >= off) ? partial[tid - off] : 0;
        __syncthreads();
        partial[tid] += v;
        __syncthreads();
    }
    int base = (tid == 0) ? 0 : partial[tid - 1];
    for (int i = start; i < end; ++i) {
        int c = cnt[i];
        offs[i] = base;
        cnt[i]  = base;   // cursor init
        base += c;
    }
    if (tid == 1023) offs[n] = partial[1023];
}

__global__ void fill_kernel(const int* __restrict__ src, const int* __restrict__ dst,
                            int* __restrict__ cursor, int* __restrict__ srcs, int E) {
    int e = blockIdx.x * blockDim.x + threadIdx.x;
    if (e < E) {
        int pos = atomicAdd(&cursor[dst[e]], 1);
        srcs[pos] = src[e];
    }
}

// ---------------- aggregation: one wave per node ----------------

__global__ __launch_bounds__(256) void aggr_kernel(const float* __restrict__ s,
                                                   const int* __restrict__ offs,
                                                   const int* __restrict__ srcs,
                                                   float* __restrict__ aggr) {
    int node = blockIdx.x * 4 + (threadIdx.x >> 6);
    if (node >= N_NODES) return;
    int lane = threadIdx.x & 63;
    int beg = offs[node], end = offs[node + 1];
    float4 acc0 = make_float4(0.f, 0.f, 0.f, 0.f);
    float4 acc1 = make_float4(0.f, 0.f, 0.f, 0.f);
    for (int e = beg; e < end; ++e) {
        const float4* row = (const float4*)(s + (size_t)srcs[e] * HIDDEN);
        float4 v0 = row[lane * 2];
        float4 v1 = row[lane * 2 + 1];
        acc0.x += v0.x; acc0.y += v0.y; acc0.z += v0.z; acc0.w += v0.w;
        acc1.x += v1.x; acc1.y += v1.y; acc1.z += v1.z; acc1.w += v1.w;
    }
    float4* o = (float4*)(aggr + (size_t)node * HIDDEN);
    o[lane * 2]     = acc0;
    o[lane * 2 + 1] = acc1;
}

// ---------------- fused GEMM: out = a*tanh(A1@B1^T + A2@B2^T) + (1-a)*s ----------------
// A1: [M,K1], B1: [HIDDEN,K1], A2: [M,HIDDEN], B2: [HIDDEN,HIDDEN], all row-major.
// 128x128 block tile, 256 threads, 8x8 micro-tile (split halves).

__global__ __launch_bounds__(256) void gemm_kernel(const float* __restrict__ A1,
                                                   const float* __restrict__ B1, int K1,
                                                   const float* __restrict__ A2,
                                                   const float* __restrict__ B2,
                                                   const float* __restrict__ sl,
                                                   const float* __restrict__ leak,
                                                   float* __restrict__ out) {
    const int BK = 16;
    __shared__ float As[BK][132];
    __shared__ float Bs[BK][132];
    const int tid = threadIdx.x;
    const int tx = tid & 15;
    const int ty = tid >> 4;
    const int m0 = blockIdx.y * 128;
    const int j0 = blockIdx.x * 128;

    float acc[8][8];
#pragma unroll
    for (int i = 0; i < 8; ++i)
#pragma unroll
        for (int j = 0; j < 8; ++j) acc[i][j] = 0.f;

#pragma unroll 1
    for (int seg = 0; seg < 2; ++seg) {
        const float* A = seg ? A2 : A1;
        const float* B = seg ? B2 : B1;
        const int K = seg ? HIDDEN : K1;
#pragma unroll 1
        for (int kb = 0; kb < K; kb += BK) {
#pragma unroll
            for (int rep = 0; rep < 2; ++rep) {
                int f   = tid + rep * 256;
                int row = f >> 2;           // 0..127
                int k4  = (f & 3) * 4;      // 0,4,8,12
                int gr  = m0 + row;
                float4 v = make_float4(0.f, 0.f, 0.f, 0.f);
                if (gr < N_NODES) v = *(const float4*)(A + (size_t)gr * K + kb + k4);
                As[k4 + 0][row] = v.x; As[k4 + 1][row] = v.y;
                As[k4 + 2][row] = v.z; As[k4 + 3][row] = v.w;
                float4 w = *(const float4*)(B + (size_t)(j0 + row) * K + kb + k4);
                Bs[k4 + 0][row] = w.x; Bs[k4 + 1][row] = w.y;
                Bs[k4 + 2][row] = w.z; Bs[k4 + 3][row] = w.w;
            }
            __syncthreads();
#pragma unroll
            for (int k = 0; k < BK; ++k) {
                float4 a0 = *(const float4*)&As[k][ty * 4];
                float4 a1 = *(const float4*)&As[k][64 + ty * 4];
                float4 b0 = *(const float4*)&Bs[k][tx * 4];
                float4 b1 = *(const float4*)&Bs[k][64 + tx * 4];
                float av[8] = {a0.x, a0.y, a0.z, a0.w, a1.x, a1.y, a1.z, a1.w};
                float bv[8] = {b0.x, b0.y, b0.z, b0.w, b1.x, b1.y, b1.z, b1.w};
#pragma unroll
                for (int i = 0; i < 8; ++i)
#pragma unroll
                    for (int j = 0; j < 8; ++j)
                        acc[i][j] = fmaf(av[i], bv[j], acc[i][j]);
            }
            __syncthreads();
        }
    }

    const float a  = leak[0];
    const float om = 1.0f - a;
#pragma unroll
    for (int ih = 0; ih < 2; ++ih) {
#pragma unroll
        for (int i = 0; i < 4; ++i) {
            int gr = m0 + ih * 64 + ty * 4 + i;
            if (gr >= N_NODES) continue;
#pragma unroll
            for (int jh = 0; jh < 2; ++jh) {
                int gc = j0 + jh * 64 + tx * 4;
                float4 sv = *(const float4*)(sl + (size_t)gr * HIDDEN + gc);
                float4 r;
                r.x = a * tanhf(acc[ih * 4 + i][jh * 4 + 0]) + om * sv.x;
                r.y = a * tanhf(acc[ih * 4 + i][jh * 4 + 1]) + om * sv.y;
                r.z = a * tanhf(acc[ih * 4 + i][jh * 4 + 2]) + om * sv.z;
                r.w = a * tanhf(acc[ih * 4 + i][jh * 4 + 3]) + om * sv.w;
                *(float4*)(out + (size_t)gr * HIDDEN + gc) = r;
            }
        }
    }
}

// ---------------- launch ----------------

extern "C" void kernel_launch(void* const* d_in, const int* in_sizes, int n_in,
                              void* d_out, int out_size, void* d_ws, size_t ws_size,
                              hipStream_t stream) {
    const int*   edge   = (const int*)d_in[0];
    const float* x      = (const float*)d_in[1];
    const float* states = (const float*)d_in[2];
    const float* Wi0    = (const float*)d_in[3];
    const float* WiR    = (const float*)d_in[4];
    const float* Wr     = (const float*)d_in[5];
    const float* leak   = (const float*)d_in[6];
    float* out = (float*)d_out;

    const int E = N_EDGES, N = N_NODES;
    const int* src = edge;
    const int* dst = edge + E;

    char* ws = (char*)d_ws;
    int* cursor = (int*)ws;            // N ints (counts -> cursor)
    int* offs   = cursor + N;          // N+1 ints
    int* srcs   = offs + N + 1;        // E ints
    size_t off_aggr = (((size_t)(N + (N + 1) + E)) * sizeof(int) + 255) & ~(size_t)255;
    float* aggr = (float*)(ws + off_aggr);

    hipMemsetAsync(cursor, 0, (size_t)N * sizeof(int), stream);
    hist_kernel<<<(E + 255) / 256, 256, 0, stream>>>(dst, cursor, E);
    scan_kernel<<<1, 1024, 0, stream>>>(cursor, offs, N);
    fill_kernel<<<(E + 255) / 256, 256, 0, stream>>>(src, dst, cursor, srcs, E);

    dim3 ggrid(HIDDEN / 128, (N + 127) / 128);
    for (int l = 0; l < NUM_LAYERS; ++l) {
        const float* sl = states + (size_t)l * N * HIDDEN;
        aggr_kernel<<<(N + 3) / 4, 256, 0, stream>>>(sl, offs, srcs, aggr);
        const float* A1 = (l == 0) ? x : out + (size_t)(l - 1) * N * HIDDEN;
        const float* B1 = (l == 0) ? Wi0 : WiR + (size_t)(l - 1) * HIDDEN * HIDDEN;
        int K1 = (l == 0) ? IN_FEAT : HIDDEN;
        const float* B2 = Wr + (size_t)l * HIDDEN * HIDDEN;
        gemm_kernel<<<ggrid, 256, 0, stream>>>(A1, B1, K1, aggr, B2, sl, leak,
                                               out + (size_t)l * N * HIDDEN);
    }
}